// Round 3
// baseline (5102.262 us; speedup 1.0000x reference)
//
#include <hip/hip_runtime.h>

typedef _Float16 h2 __attribute__((ext_vector_type(2)));
typedef float f4 __attribute__((ext_vector_type(4)));

static constexpr int NB = 128;   // batch
static constexpr int NT = 4096;  // time
static constexpr int NI = 64;    // input
static constexpr int NH = 256;   // hidden
static constexpr int NO = 64;    // output
static constexpr int CHUNK = 16; // timesteps of x staged per LDS chunk

union H2I { int i; h2 h; };

__device__ __forceinline__ float fdot2(h2 a, h2 b, float c) {
#if __has_builtin(__builtin_amdgcn_fdot2)
    return __builtin_amdgcn_fdot2(a, b, c, false);
#else
    return c + (float)a[0] * (float)b[0] + (float)a[1] * (float)b[1];
#endif
}

// broadcast one lane's dword to all lanes (lands in SGPR; feeds VALU as the 1 scalar src)
__device__ __forceinline__ int bcast(int v, int l) {
#if __has_builtin(__builtin_amdgcn_readlane)
    return __builtin_amdgcn_readlane(v, l);
#else
    return __shfl(v, l, 64);
#endif
}

__device__ __forceinline__ int pack2(float a, float b) {
    H2I u;
    u.h[0] = (_Float16)a;
    u.h[1] = (_Float16)b;
    return u.i;
}

__device__ __forceinline__ float fast_tanh(float x) {
#if __has_builtin(__builtin_amdgcn_exp2f)
    float e = __builtin_amdgcn_exp2f(x * 2.885390081777927f); // 2*log2(e)
#else
    float e = exp2f(x * 2.885390081777927f);
#endif
#if __has_builtin(__builtin_amdgcn_rcpf)
    return 1.0f - 2.0f * __builtin_amdgcn_rcpf(e + 1.0f);
#else
    return 1.0f - 2.0f / (e + 1.0f);
#endif
}

__global__ __launch_bounds__(256, 1) void rnn_persist(
    const float* __restrict__ x,    // [B,T,I]
    const float* __restrict__ wih,  // [H,I]
    const float* __restrict__ whhg, // [H,H]
    const float* __restrict__ bih,  // [H]
    const float* __restrict__ bhh,  // [H]
    const float* __restrict__ wy,   // [O,H]
    const float* __restrict__ by,   // [O]
    float* __restrict__ out)        // [B,O]
{
    __shared__ int hbuf[2][NH / 2];          // h as fp16 pairs: 128 dwords
    __shared__ int xbuf[2][CHUNK * NI / 2];  // x chunk as fp16 pairs: 512 dwords
    __shared__ float hf[NH];

    const int j = threadIdx.x;   // output unit owned by this thread
    const int lane = j & 63;
    const int b = blockIdx.x;    // chain owned by this block

    // ---- weights to registers as fp16 pairs (cold path) ----
    h2 whh[NH / 2];  // 128 VGPRs: row j of W_hh
    {
        const f4* src = (const f4*)(whhg + (size_t)j * NH);
#pragma unroll
        for (int q = 0; q < NH / 4; ++q) {
            f4 v = src[q];
            H2I u0, u1;
            u0.i = pack2(v.x, v.y);
            u1.i = pack2(v.z, v.w);
            whh[2 * q] = u0.h;
            whh[2 * q + 1] = u1.h;
        }
    }
    h2 wi[NI / 2];  // 32 VGPRs: row j of W_ih
    {
        const f4* src = (const f4*)(wih + (size_t)j * NI);
#pragma unroll
        for (int q = 0; q < NI / 4; ++q) {
            f4 v = src[q];
            H2I u0, u1;
            u0.i = pack2(v.x, v.y);
            u1.i = pack2(v.z, v.w);
            wi[2 * q] = u0.h;
            wi[2 * q + 1] = u1.h;
        }
    }
    const float bias = bih[j] + bhh[j];

    const float* xb = x + (size_t)b * NT * NI;

    // ---- stage x chunk 0: 16 steps * 64 f32 -> fp16 pairs, 2 dwords/thread ----
    {
        f4 v = ((const f4*)xb)[j];
        xbuf[0][2 * j] = pack2(v.x, v.y);
        xbuf[0][2 * j + 1] = pack2(v.z, v.w);
    }
    if (j < NH / 2) hbuf[0][j] = 0;  // h(0) = 0
    __syncthreads();

    float hval = 0.f;
    f4 xnext;
    int p = 0;

    for (int t = 0; t < NT; ++t) {
        const int s = t & (CHUNK - 1);
        const int c = t >> 4;

        if (s == 0 && t + CHUNK < NT) {
            xnext = ((const f4*)(xb + (size_t)(t + CHUNK) * NI))[j];
        }

        // distributed loads: lane l holds h[4l..4l+3] (2 dwords), x dword (lane&31)
        const int2 hd = ((const int2*)hbuf[p])[lane];       // 1x ds_read_b64 per wave
        const int xd = xbuf[c & 1][s * (NI / 2) + (lane & 31)];  // 1x ds_read_b32 per wave

        float acc[4] = {bias, 0.f, 0.f, 0.f};

        // x projection: 32 pairs via readlane broadcast
#pragma unroll
        for (int q = 0; q < NI / 2; ++q) {
            H2I u;
            u.i = bcast(xd, q);
            acc[q & 3] = fdot2(wi[q], u.h, acc[q & 3]);
        }
        // recurrent matvec: 128 pairs via readlane broadcast
#pragma unroll
        for (int q = 0; q < NH / 2; ++q) {
            H2I u;
            u.i = bcast((q & 1) ? hd.y : hd.x, q >> 1);
            acc[q & 3] = fdot2(whh[q], u.h, acc[q & 3]);
        }

        hval = fast_tanh((acc[0] + acc[1]) + (acc[2] + acc[3]));

        // publish my h (one fp16) into the other buffer
        ((_Float16*)hbuf[p ^ 1])[j] = (_Float16)hval;

        // commit prefetched x chunk at chunk end
        if (s == CHUNK - 1 && t + 1 < NT) {
            xbuf[(c + 1) & 1][2 * j] = pack2(xnext.x, xnext.y);
            xbuf[(c + 1) & 1][2 * j + 1] = pack2(xnext.z, xnext.w);
        }

        __syncthreads();
        p ^= 1;
    }

    // ---- epilogue: y = h_last @ W_y^T + b_y ----
    hf[j] = hval;
    __syncthreads();
    if (j < NO) {
        float acc = by[j];
        const f4* wrow = (const f4*)(wy + (size_t)j * NH);
        const f4* hp = (const f4*)hf;
#pragma unroll
        for (int q = 0; q < NH / 4; ++q) {
            f4 w = wrow[q];
            f4 h = hp[q];
            acc += w.x * h.x + w.y * h.y + w.z * h.z + w.w * h.w;
        }
        out[b * NO + j] = acc;
    }
}

extern "C" void kernel_launch(void* const* d_in, const int* in_sizes, int n_in,
                              void* d_out, int out_size, void* d_ws, size_t ws_size,
                              hipStream_t stream) {
    const float* x   = (const float*)d_in[0];
    const float* wih = (const float*)d_in[1];
    const float* whh = (const float*)d_in[2];
    const float* bih = (const float*)d_in[3];
    const float* bhh = (const float*)d_in[4];
    const float* wy  = (const float*)d_in[5];
    const float* by  = (const float*)d_in[6];
    float* out = (float*)d_out;

    rnn_persist<<<dim3(NB), dim3(256), 0, stream>>>(x, wih, whh, bih, bhh, wy, by, out);
}

// Round 4
// 2632.073 us; speedup vs baseline: 1.9385x; 1.9385x over previous
//
#include <hip/hip_runtime.h>

typedef _Float16 h2 __attribute__((ext_vector_type(2)));
typedef float f4 __attribute__((ext_vector_type(4)));

static constexpr int NB = 128;   // batch
static constexpr int NT = 4096;  // time
static constexpr int NI = 64;    // input
static constexpr int NH = 256;   // hidden
static constexpr int NO = 64;    // output
static constexpr int CHUNK = 16; // timesteps of x staged per LDS chunk

union H2I { int i; h2 h; };

__device__ __forceinline__ float fdot2(h2 a, h2 b, float c) {
#if __has_builtin(__builtin_amdgcn_fdot2)
    return __builtin_amdgcn_fdot2(a, b, c, false);
#else
    return c + (float)a[0] * (float)b[0] + (float)a[1] * (float)b[1];
#endif
}

__device__ __forceinline__ int pack2(float a, float b) {
    H2I u;
    u.h[0] = (_Float16)a;
    u.h[1] = (_Float16)b;
    return u.i;
}
__device__ __forceinline__ h2 toh2(int v) { H2I u; u.i = v; return u.h; }

// xor-8 combine on the VALU pipe (DPP row_ror:8 == lane^8 within 16-lane rows)
__device__ __forceinline__ float red_xor8(float v) {
#if __has_builtin(__builtin_amdgcn_mov_dpp)
    int o = __builtin_amdgcn_mov_dpp(__float_as_int(v), 0x128, 0xF, 0xF, true);
    return v + __int_as_float(o);
#else
    return v + __shfl_xor(v, 8, 64);
#endif
}
// xor-16 combine via ds_swizzle BitMode (xor=16, and=0x1F) -> 0x401F
__device__ __forceinline__ float red_xor16(float v) {
#if __has_builtin(__builtin_amdgcn_ds_swizzle)
    int o = __builtin_amdgcn_ds_swizzle(__float_as_int(v), 0x401F);
    return v + __int_as_float(o);
#else
    return v + __shfl_xor(v, 16, 64);
#endif
}

__device__ __forceinline__ float fast_tanh(float x) {
#if __has_builtin(__builtin_amdgcn_exp2f)
    float e = __builtin_amdgcn_exp2f(x * 2.885390081777927f); // 2*log2(e)
#else
    float e = exp2f(x * 2.885390081777927f);
#endif
#if __has_builtin(__builtin_amdgcn_rcpf)
    return 1.0f - 2.0f * __builtin_amdgcn_rcpf(e + 1.0f);
#else
    return 1.0f - 2.0f / (e + 1.0f);
#endif
}

__global__ __launch_bounds__(256, 1) void rnn_persist(
    const float* __restrict__ x,    // [B,T,I]
    const float* __restrict__ wih,  // [H,I]
    const float* __restrict__ whhg, // [H,H]
    const float* __restrict__ bih,  // [H]
    const float* __restrict__ bhh,  // [H]
    const float* __restrict__ wy,   // [O,H]
    const float* __restrict__ by,   // [O]
    float* __restrict__ out)        // [B,O]
{
    // h stored as fp16, chunk-swizzled: logical 16B chunk (qh, c) lives at
    // byte 64*qh + 16*(c ^ (qh&3)) -> the 8 lane-groups' reads hit disjoint bank quads.
    __shared__ int hbuf[2][NH / 2];          // 2 x 512 B
    __shared__ int xbuf[2][CHUNK * NI / 2];  // 2 x 2 KB (fp16 pairs)
    __shared__ float hf[NH];

    const int tid = threadIdx.x;
    const int w = tid >> 6;      // wave: owns outputs [64w, 64w+64)
    const int l = tid & 63;
    const int r = l & 7;         // output sub-block within wave
    const int q = l >> 3;        // K-eighth owned by this lane (h[32q..32q+31])
    const int b5 = l >> 5;
    const bool hi32 = (l >= 32);
    const int b = blockIdx.x;    // chain owned by this block

    // ---- weights to registers (cold): rows j0..j0+7, my K-slice ----
    h2 whh[8][16];  // 128 VGPRs: W_hh[j0+a][32q .. 32q+31]
    h2 wi[8][4];    //  32 VGPRs: W_ih[j0+a][8q .. 8q+7]
    const int j0 = 64 * w + 8 * r;
#pragma unroll
    for (int a = 0; a < 8; ++a) {
        const f4* src = (const f4*)(whhg + (size_t)(j0 + a) * NH + 32 * q);
#pragma unroll
        for (int u = 0; u < 8; ++u) {
            f4 v = src[u];
            whh[a][2 * u]     = toh2(pack2(v.x, v.y));
            whh[a][2 * u + 1] = toh2(pack2(v.z, v.w));
        }
        const f4* s2 = (const f4*)(wih + (size_t)(j0 + a) * NI + 8 * q);
#pragma unroll
        for (int u = 0; u < 2; ++u) {
            f4 v = s2[u];
            wi[a][2 * u]     = toh2(pack2(v.x, v.y));
            wi[a][2 * u + 1] = toh2(pack2(v.z, v.w));
        }
    }
    // final outputs this lane carries after reduction: jb .. jb+3
    const int jb = j0 + 4 * b5;
    float bias_r[4];
#pragma unroll
    for (int i = 0; i < 4; ++i) bias_r[i] = bih[jb + i] + bhh[jb + i];

    // ---- LDS addresses ----
    const int sw = q & 3;
    int hoff[4];
#pragma unroll
    for (int c = 0; c < 4; ++c) hoff[c] = 64 * q + 16 * (c ^ sw);
    const int qh = 2 * w + (r >> 2);
    const int pub_off = 64 * qh + 16 * ((r & 3) ^ (qh & 3)) + 8 * b5;
    const bool writer = (l & 24) == 0;  // one lane per (r, b5)

    const float* xb = x + (size_t)b * NT * NI;

    // ---- stage x chunk 0 (1024 f32 -> fp16 pairs; 4 f32/thread) ----
    {
        f4 v = ((const f4*)xb)[tid];
        xbuf[0][2 * tid]     = pack2(v.x, v.y);
        xbuf[0][2 * tid + 1] = pack2(v.z, v.w);
    }
    if (tid < NH / 2) hbuf[0][tid] = 0;  // h(0) = 0 (swizzle irrelevant for zeros)
    __syncthreads();

    f4 xnext;
    int p = 0;

#pragma unroll 1
    for (int t = 0; t < NT; ++t) {
        const int s = t & (CHUNK - 1);
        const int c = t >> 4;

        if (s == 0 && t + CHUNK < NT) {
            xnext = ((const f4*)(xb + (size_t)(t + CHUNK) * NI))[tid];
        }

        // distributed reads: x slice (16B) + my h K-eighth (4 x 16B, swizzled)
        const char* hbp = (const char*)hbuf[p];
        const int4 xv = *(const int4*)((const char*)xbuf[c & 1] + 128 * s + 16 * q);
        const int4 h0 = *(const int4*)(hbp + hoff[0]);
        const int4 h1 = *(const int4*)(hbp + hoff[1]);
        const int4 h2v = *(const int4*)(hbp + hoff[2]);
        const int4 h3 = *(const int4*)(hbp + hoff[3]);

        float acc[8];
#pragma unroll
        for (int a = 0; a < 8; ++a) acc[a] = 0.f;

        // x projection over my 8 inputs (4 pairs)
#pragma unroll
        for (int a = 0; a < 8; ++a) {
            acc[a] = fdot2(wi[a][0], toh2(xv.x), acc[a]);
            acc[a] = fdot2(wi[a][1], toh2(xv.y), acc[a]);
            acc[a] = fdot2(wi[a][2], toh2(xv.z), acc[a]);
            acc[a] = fdot2(wi[a][3], toh2(xv.w), acc[a]);
        }
        // recurrent matvec over my 32 h values (16 pairs)
        const int hc[16] = {h0.x, h0.y, h0.z, h0.w, h1.x, h1.y, h1.z, h1.w,
                            h2v.x, h2v.y, h2v.z, h2v.w, h3.x, h3.y, h3.z, h3.w};
#pragma unroll
        for (int kk = 0; kk < 16; ++kk) {
            const h2 hv = toh2(hc[kk]);
#pragma unroll
            for (int a = 0; a < 8; ++a) acc[a] = fdot2(whh[a][kk], hv, acc[a]);
        }

        // ---- in-wave reduction over lane bits 3,4,5 ----
        float th[4];
#pragma unroll
        for (int i = 0; i < 4; ++i) {
            // bit5 pair-combine: finishes acc[i] on lanes<32 and acc[i+4] on lanes>=32
            float cc = hi32 ? acc[i + 4] : acc[i];
            float dd = hi32 ? acc[i] : acc[i + 4];
            cc += __shfl_xor(dd, 32, 64);
            cc = red_xor8(cc);   // bit3 (VALU/DPP)
            cc = red_xor16(cc);  // bit4 (ds_swizzle)
            th[i] = fast_tanh(cc + bias_r[i]);
        }

        // publish my 4 outputs (jb..jb+3) as fp16 into the other h buffer
        if (writer) {
            int2 pk;
            pk.x = pack2(th[0], th[1]);
            pk.y = pack2(th[2], th[3]);
            *(int2*)((char*)hbuf[p ^ 1] + pub_off) = pk;
            if (t == NT - 1) {
                f4 hv;
                hv.x = th[0]; hv.y = th[1]; hv.z = th[2]; hv.w = th[3];
                *(f4*)(&hf[jb]) = hv;
            }
        }

        // commit prefetched x chunk
        if (s == CHUNK - 1 && t + 1 < NT) {
            xbuf[(c + 1) & 1][2 * tid]     = pack2(xnext.x, xnext.y);
            xbuf[(c + 1) & 1][2 * tid + 1] = pack2(xnext.z, xnext.w);
        }

        __syncthreads();
        p ^= 1;
    }

    // ---- epilogue: y = h_last @ W_y^T + b_y (hf holds f32 h_last) ----
    if (tid < NO) {
        float accy = by[tid];
        const f4* wrow = (const f4*)(wy + (size_t)tid * NH);
        const f4* hp = (const f4*)hf;
#pragma unroll
        for (int u = 0; u < NH / 4; ++u) {
            f4 wv = wrow[u];
            f4 hv = hp[u];
            accy += wv.x * hv.x + wv.y * hv.y + wv.z * hv.z + wv.w * hv.w;
        }
        out[b * NO + tid] = accy;
    }
}

extern "C" void kernel_launch(void* const* d_in, const int* in_sizes, int n_in,
                              void* d_out, int out_size, void* d_ws, size_t ws_size,
                              hipStream_t stream) {
    const float* x   = (const float*)d_in[0];
    const float* wih = (const float*)d_in[1];
    const float* whh = (const float*)d_in[2];
    const float* bih = (const float*)d_in[3];
    const float* bhh = (const float*)d_in[4];
    const float* wy  = (const float*)d_in[5];
    const float* by  = (const float*)d_in[6];
    float* out = (float*)d_out;

    rnn_persist<<<dim3(NB), dim3(256), 0, stream>>>(x, wih, whh, bih, bhh, wy, by, out);
}